// Round 3
// baseline (1673.250 us; speedup 1.0000x reference)
//
#include <hip/hip_runtime.h>
#include <hip/hip_bf16.h>

// ---------------------------------------------------------------------------
// Decoder step: attention (enc@W1^T fused tanh/softmax/ctx) + GRU + fc head.
// R2: attention fully fused, ZERO enc staging. enc A-fragments are loaded
// straight from global f32 and packed to bf16 in registers (each element is
// consumed exactly once -> LDS staging was pure overhead). Barrier-free
// K-loop, then tanh/softmax/ctx all in-block. ctx re-reads enc (L3-warm).
// ---------------------------------------------------------------------------

typedef __attribute__((ext_vector_type(4))) float floatx4;
typedef __attribute__((ext_vector_type(8))) short short8;

#define DEV static __device__ __forceinline__

DEV unsigned short f2bf(float f) {          // fp32 -> bf16, round-nearest-even
  unsigned u = __float_as_uint(f);
  u = u + 0x7fffu + ((u >> 16) & 1u);
  return (unsigned short)(u >> 16);
}
DEV float bf2f(unsigned short s) { return __uint_as_float(((unsigned)s) << 16); }
DEV float tanh_fast(float x) {              // saturates correctly at +-inf
  float e = __expf(2.f * x);
  return 1.f - 2.f / (e + 1.f);
}
DEV float sigmoid_fast(float x) { return 1.f / (1.f + __expf(-x)); }

DEV unsigned pk2(float a, float b) {        // 2x f32 -> packed bf16x2 (RNE)
  float2 f;
  f.x = a;
  f.y = b;
  __hip_bfloat162 h = __float22bfloat162_rn(f);
  return *(unsigned*)&h;
}
DEV short8 cvt8(float4 lo, float4 hi) {     // 8x f32 -> bf16x8 frag
  union {
    unsigned u[4];
    short8 s;
  } r;
  r.u[0] = pk2(lo.x, lo.y);
  r.u[1] = pk2(lo.z, lo.w);
  r.u[2] = pk2(hi.x, hi.y);
  r.u[3] = pk2(hi.z, hi.w);
  return r.s;
}

// ---------------------------------------------------------------------------
// Fused prep: all fp32->bf16 padded converts + bias folds + embedding gather
// in ONE launch. Segments dispatched by blockIdx ranges.
// ---------------------------------------------------------------------------
DEV void convpad_body(const float* __restrict__ src,
                      unsigned short* __restrict__ dst,
                      int idx, int Nsrc, int Kin, int Kp) {
  int n = idx / Kp, k = idx - n * Kp;
  float v = (k < Kin && n < Nsrc) ? src[(size_t)n * Kin + k] : 0.f;
  dst[idx] = f2bf(v);
}

#define PB_W1 1024
#define PB_W2 1024
#define PB_WIH 4992
#define PB_WHH 3072
#define PB_FC1 768
#define PB_FC2 192
#define PB_HID 4096
#define PB_EMB 2560
#define PB_BIAS 2
#define PREP_BLOCKS (PB_W1 + PB_W2 + PB_WIH + PB_WHH + PB_FC1 + PB_FC2 + PB_HID + PB_EMB + PB_BIAS)

__global__ void prep_all(
    const float* __restrict__ W1w, unsigned short* __restrict__ W1bf,
    const float* __restrict__ W2w, unsigned short* __restrict__ W2bf,
    const float* __restrict__ wih, unsigned short* __restrict__ wihbf,
    const float* __restrict__ whh, unsigned short* __restrict__ whhbf,
    const float* __restrict__ fc1w, unsigned short* __restrict__ fc1wbf,
    const float* __restrict__ fc2w, unsigned short* __restrict__ fc2wbf,
    const float* __restrict__ hidden, unsigned short* __restrict__ hidbf,
    const int* __restrict__ x, const float* __restrict__ embt,
    unsigned short* __restrict__ gin,
    const float* __restrict__ W1b, const float* __restrict__ W2b,
    float* __restrict__ keyb,
    const float* __restrict__ fc1b, float* __restrict__ fc1bp) {
  int bid = blockIdx.x;
  int tid = threadIdx.x;
  if (bid < PB_W1) {
    convpad_body(W1w, W1bf, bid * 256 + tid, 512, 512, 512);
    return;
  }
  bid -= PB_W1;
  if (bid < PB_W2) {
    convpad_body(W2w, W2bf, bid * 256 + tid, 512, 512, 512);
    return;
  }
  bid -= PB_W2;
  if (bid < PB_WIH) {
    convpad_body(wih, wihbf, bid * 256 + tid, 1536, 812, 832);
    return;
  }
  bid -= PB_WIH;
  if (bid < PB_WHH) {
    convpad_body(whh, whhbf, bid * 256 + tid, 1536, 512, 512);
    return;
  }
  bid -= PB_WHH;
  if (bid < PB_FC1) {
    convpad_body(fc1w, fc1wbf, bid * 256 + tid, 300, 512, 512);
    return;
  }
  bid -= PB_FC1;
  if (bid < PB_FC2) {
    convpad_body(fc2w, fc2wbf, bid * 256 + tid, 128, 300, 384);
    return;
  }
  bid -= PB_FC2;
  if (bid < PB_HID) {
    convpad_body(hidden, hidbf, bid * 256 + tid, 2048, 512, 512);
    return;
  }
  bid -= PB_HID;
  if (bid < PB_EMB) {
    int idx = bid * 256 + tid;            // 2048 * 320
    int b = idx / 320, e = idx - b * 320;
    float v = (e < 300) ? embt[(size_t)x[b] * 300 + e] : 0.f;
    gin[(size_t)b * 832 + 512 + e] = f2bf(v);
    return;
  }
  bid -= PB_EMB;
  {
    int i = bid * 256 + tid;
    if (i < 512) keyb[i] = W1b[i] + W2b[i];   // W1_b + W2_b folded into key
    if (i < 384) fc1bp[i] = (i < 300) ? fc1b[i] : 0.f;
  }
}

// ---------------------------------------------------------------------------
// Generic bf16 GEMM: C[M,N] = A[M,K] @ B[N,K]^T + bias[n].
// 256 threads, block tile 128x128, wave tile 64x64, XOR-swizzled LDS.
// EPI 0: f32 store.  EPI 1: leaky_relu(0.01) -> bf16 store.
// ---------------------------------------------------------------------------
template <int EPI>
__global__ __launch_bounds__(256, 3) void gemm_bt(
    const unsigned short* __restrict__ A, int lda,
    const unsigned short* __restrict__ Bm, int ldb,
    const float* __restrict__ bias,
    void* __restrict__ Cp, int ldc, int K) {
  __shared__ unsigned short As[128 * 64];
  __shared__ unsigned short Bs[128 * 64];
  int tid = threadIdx.x;
  int bm = blockIdx.x * 128, bn = blockIdx.y * 128;
  int lane = tid & 63, wave = tid >> 6;
  int l15 = lane & 15, l4 = lane >> 4;
  int wm = (wave >> 1) * 64, wn = (wave & 1) * 64;

  floatx4 zero = {0.f, 0.f, 0.f, 0.f};
  floatx4 acc[4][4];
#pragma unroll
  for (int i = 0; i < 4; ++i)
#pragma unroll
    for (int j = 0; j < 4; ++j) acc[i][j] = zero;

  int row = tid >> 1;                 // staging: thread -> (row, 4 granules)
  int gc0 = (tid & 1) * 4;
  const unsigned short* Aptr = A + (size_t)(bm + row) * lda + gc0 * 8;
  const unsigned short* Bptr = Bm + (size_t)(bn + row) * ldb + gc0 * 8;
  int rslot7 = row & 7, lslot7 = l15 & 7;

  int nk = K >> 6;
  for (int kt = 0; kt < nk; ++kt) {
#pragma unroll
    for (int i = 0; i < 4; ++i) {
      int slot = (gc0 + i) ^ rslot7;
      *(uint4*)&As[row * 64 + slot * 8] = *(const uint4*)(Aptr + kt * 64 + i * 8);
      *(uint4*)&Bs[row * 64 + slot * 8] = *(const uint4*)(Bptr + kt * 64 + i * 8);
    }
    __syncthreads();
#pragma unroll
    for (int ks = 0; ks < 2; ++ks) {
      int slot = (ks * 4 + l4) ^ lslot7;
      short8 av[4], bv[4];
#pragma unroll
      for (int mt = 0; mt < 4; ++mt)
        av[mt] = *(const short8*)&As[(wm + mt * 16 + l15) * 64 + slot * 8];
#pragma unroll
      for (int nt = 0; nt < 4; ++nt)
        bv[nt] = *(const short8*)&Bs[(wn + nt * 16 + l15) * 64 + slot * 8];
#pragma unroll
      for (int mt = 0; mt < 4; ++mt)
#pragma unroll
        for (int nt = 0; nt < 4; ++nt)
          acc[mt][nt] = __builtin_amdgcn_mfma_f32_16x16x32_bf16(
              av[mt], bv[nt], acc[mt][nt], 0, 0, 0);
    }
    __syncthreads();
  }

#pragma unroll
  for (int nt = 0; nt < 4; ++nt) {
    int n = bn + wn + nt * 16 + l15;
    float bvv = bias[n];
#pragma unroll
    for (int mt = 0; mt < 4; ++mt) {
#pragma unroll
      for (int r = 0; r < 4; ++r) {
        int m = bm + wm + mt * 16 + l4 * 4 + r;
        float v = acc[mt][nt][r] + bvv;
        if (EPI == 1) {
          v = v > 0.f ? v : 0.01f * v;
          ((unsigned short*)Cp)[(size_t)m * ldc + n] = f2bf(v);
        } else {
          ((float*)Cp)[(size_t)m * ldc + n] = v;
        }
      }
    }
  }
}

// ---------------------------------------------------------------------------
// attn_fused: one block per batch b (512 threads = 8 waves).
//  GEMM: score_pre[128,512] = enc[b] @ W1^T. Wave w owns cols [w*64,w*64+64),
//        all 128 rows (acc[8][4]). A-frags load DIRECTLY from global f32 enc,
//        packed to bf16 via v_cvt_pk (each element used once -> no staging,
//        no LDS, no barriers in the K-loop). B-frags from L2-hot W1 bf16.
//  epi:  logits[s] = sum_j tanh(score+key[j])*Vw[j]: shfl-reduce over l15,
//        per-wave partials in LDS, wave-0 fixed-order sum (deterministic) +
//        softmax -> attw. ctx: s-range split across waves (16 s each, float4
//        loads of enc, L3-warm), LDS partial reduce -> gin[:, 0:512] bf16.
// ---------------------------------------------------------------------------
__global__ __launch_bounds__(512, 2) void attn_fused(
    const float* __restrict__ enc, const unsigned short* __restrict__ W1b16,
    const float* __restrict__ key, const float* __restrict__ Vw,
    unsigned short* __restrict__ gin) {
  __shared__ float lds_part[8 * 128];   // per-wave logit partials
  __shared__ float attw[128];           // softmax weights
  __shared__ float ctxp[8 * 512];       // per-wave ctx partials

  int b = blockIdx.x;
  int tid = threadIdx.x;
  int wave = tid >> 6, lane = tid & 63;
  int l15 = lane & 15, l4 = lane >> 4;
  int n0 = wave * 64;
  const float* encb = enc + (size_t)b * 128 * 512;

  floatx4 zero = {0.f, 0.f, 0.f, 0.f};
  floatx4 acc[8][4];
#pragma unroll
  for (int i = 0; i < 8; ++i)
#pragma unroll
    for (int j = 0; j < 4; ++j) acc[i][j] = zero;

  const float* abase = encb + (size_t)l15 * 512 + l4 * 8;
  const unsigned short* bbase = W1b16 + (size_t)(n0 + l15) * 512 + l4 * 8;

#pragma unroll 2
  for (int kt = 0; kt < 16; ++kt) {
    short8 bv[4];
#pragma unroll
    for (int nt = 0; nt < 4; ++nt)
      bv[nt] = *(const short8*)(bbase + (size_t)nt * 16 * 512 + kt * 32);
#pragma unroll
    for (int mt = 0; mt < 8; ++mt) {
      const float* ap = abase + mt * 16 * 512 + kt * 32;
      float4 lo = *(const float4*)ap;
      float4 hi = *(const float4*)(ap + 4);
      short8 av = cvt8(lo, hi);
#pragma unroll
      for (int nt = 0; nt < 4; ++nt)
        acc[mt][nt] = __builtin_amdgcn_mfma_f32_16x16x32_bf16(
            av, bv[nt], acc[mt][nt], 0, 0, 0);
    }
  }

  // ---- logits: per-wave 64-col dot of tanh(score+key) with Vw ----
  float kb[4], vwl[4];
#pragma unroll
  for (int nt = 0; nt < 4; ++nt) {
    int col = n0 + nt * 16 + l15;
    kb[nt] = key[(size_t)b * 512 + col];
    vwl[nt] = Vw[col];
  }
#pragma unroll
  for (int mt = 0; mt < 8; ++mt) {
#pragma unroll
    for (int r = 0; r < 4; ++r) {
      float c = 0.f;
#pragma unroll
      for (int nt = 0; nt < 4; ++nt)
        c += tanh_fast(acc[mt][nt][r] + kb[nt]) * vwl[nt];
      c += __shfl_xor(c, 1, 64);
      c += __shfl_xor(c, 2, 64);
      c += __shfl_xor(c, 4, 64);
      c += __shfl_xor(c, 8, 64);
      if (l15 == 0) lds_part[wave * 128 + mt * 16 + l4 * 4 + r] = c;
    }
  }
  __syncthreads();

  // ---- softmax over S=128 (wave 0; fixed-order sum: deterministic) ----
  if (wave == 0) {
    float l0 = 0.f, l1 = 0.f;
#pragma unroll
    for (int w = 0; w < 8; ++w) {
      l0 += lds_part[w * 128 + lane];
      l1 += lds_part[w * 128 + 64 + lane];
    }
    float mx = fmaxf(l0, l1);
#pragma unroll
    for (int o = 32; o >= 1; o >>= 1) mx = fmaxf(mx, __shfl_xor(mx, o, 64));
    float e0 = __expf(l0 - mx), e1 = __expf(l1 - mx);
    float s = e0 + e1;
#pragma unroll
    for (int o = 32; o >= 1; o >>= 1) s += __shfl_xor(s, o, 64);
    float inv = 1.f / s;
    attw[lane] = e0 * inv;
    attw[lane + 64] = e1 * inv;
  }
  __syncthreads();

  // ---- ctx: wave w handles s in [w*16, w*16+16); cols split 2x float4 ----
  {
    float4 cx0 = {0.f, 0.f, 0.f, 0.f}, cx1 = {0.f, 0.f, 0.f, 0.f};
    const float* ep = encb + (size_t)(wave * 16) * 512 + lane * 4;
#pragma unroll 4
    for (int i = 0; i < 16; ++i) {
      float w = attw[wave * 16 + i];
      float4 v0 = *(const float4*)(ep + (size_t)i * 512);
      float4 v1 = *(const float4*)(ep + (size_t)i * 512 + 256);
      cx0.x += w * v0.x;
      cx0.y += w * v0.y;
      cx0.z += w * v0.z;
      cx0.w += w * v0.w;
      cx1.x += w * v1.x;
      cx1.y += w * v1.y;
      cx1.z += w * v1.z;
      cx1.w += w * v1.w;
    }
    *(float4*)&ctxp[wave * 512 + lane * 4] = cx0;
    *(float4*)&ctxp[wave * 512 + 256 + lane * 4] = cx1;
  }
  __syncthreads();

  {
    int h = tid;                        // 512 cols
    float s = 0.f;
#pragma unroll
    for (int w = 0; w < 8; ++w) s += ctxp[w * 512 + h];
    gin[(size_t)b * 832 + h] = f2bf(s);
  }
}

// ---------------------------------------------------------------------------
// GRU elementwise: gates from gi/gh (f32), h0 in f32; writes h_new (f32 to
// d_out) and bf16 copy for the fc1 GEMM.
// ---------------------------------------------------------------------------
__global__ void gru_kernel(const float* __restrict__ gi,
                           const float* __restrict__ gh,
                           const float* __restrict__ hidden,
                           float* __restrict__ outh,
                           unsigned short* __restrict__ hnewbf) {
  int idx = blockIdx.x * 256 + threadIdx.x;   // 2048*512
  int b = idx >> 9, h = idx & 511;
  const float* gib = gi + (size_t)b * 1536;
  const float* ghb = gh + (size_t)b * 1536;
  float r = sigmoid_fast(gib[h] + ghb[h]);
  float z = sigmoid_fast(gib[512 + h] + ghb[512 + h]);
  float n = tanh_fast(gib[1024 + h] + r * ghb[1024 + h]);
  float h0 = hidden[idx];
  float hn = (1.f - z) * n + z * h0;
  outh[idx] = hn;
  hnewbf[idx] = f2bf(hn);
}

// ---------------------------------------------------------------------------
extern "C" void kernel_launch(void* const* d_in, const int* in_sizes, int n_in,
                              void* d_out, int out_size, void* d_ws,
                              size_t ws_size, hipStream_t stream) {
  const int* x = (const int*)d_in[0];
  const float* hidden = (const float*)d_in[1];   // (1,2048,512)
  const float* enc = (const float*)d_in[2];      // (2048,128,512)
  const float* embt = (const float*)d_in[3];     // (128,300)
  const float* W1w = (const float*)d_in[4];
  const float* W1b = (const float*)d_in[5];
  const float* W2w = (const float*)d_in[6];
  const float* W2b = (const float*)d_in[7];
  const float* Vw = (const float*)d_in[8];
  // d_in[9] = V_b: unused (softmax shift-invariant)
  const float* wih = (const float*)d_in[10];     // (1536,812)
  const float* whh = (const float*)d_in[11];     // (1536,512)
  const float* bih = (const float*)d_in[12];
  const float* bhh = (const float*)d_in[13];
  const float* fc1w = (const float*)d_in[14];    // (300,512)
  const float* fc1b = (const float*)d_in[15];
  const float* fc2w = (const float*)d_in[16];    // (128,300)
  const float* fc2b = (const float*)d_in[17];

  float* out_y = (float*)d_out;                  // (2048,128)
  float* out_h = out_y + 2048 * 128;             // (2048,512)

  char* ws = (char*)d_ws;
  size_t o = 0;
  auto alloc = [&](size_t bytes) {
    size_t r = o;
    o += (bytes + 255) & ~(size_t)255;
    return r;
  };
  unsigned short* W1bf = (unsigned short*)(ws + alloc(512 * 512 * 2));
  unsigned short* W2bf = (unsigned short*)(ws + alloc(512 * 512 * 2));
  unsigned short* wihbf = (unsigned short*)(ws + alloc(1536 * 832 * 2));
  unsigned short* whhbf = (unsigned short*)(ws + alloc(1536 * 512 * 2));
  unsigned short* fc1wbf = (unsigned short*)(ws + alloc(384 * 512 * 2));
  unsigned short* fc2wbf = (unsigned short*)(ws + alloc(128 * 384 * 2));
  unsigned short* hidbf = (unsigned short*)(ws + alloc(2048 * 512 * 2));
  unsigned short* ginbf = (unsigned short*)(ws + alloc((size_t)2048 * 832 * 2));
  float* keyb = (float*)(ws + alloc(512 * 4));
  float* fc1bp = (float*)(ws + alloc(384 * 4));
  float* key = (float*)(ws + alloc((size_t)2048 * 512 * 4));
  float* gi = (float*)(ws + alloc((size_t)2048 * 1536 * 4));
  float* gh = (float*)(ws + alloc((size_t)2048 * 1536 * 4));
  unsigned short* hnewbf = (unsigned short*)(ws + alloc(2048 * 512 * 2));
  unsigned short* a1bf = (unsigned short*)(ws + alloc((size_t)2048 * 384 * 2));

  // ---- prep: all bf16 conversions + biases + embedding in ONE launch ----
  prep_all<<<PREP_BLOCKS, 256, 0, stream>>>(
      W1w, W1bf, W2w, W2bf, wih, wihbf, whh, whhbf, fc1w, fc1wbf, fc2w, fc2wbf,
      hidden, hidbf, x, embt, ginbf, W1b, W2b, keyb, fc1b, fc1bp);

  // ---- key = h0 @ W2^T + (W2_b + W1_b) ----
  gemm_bt<0><<<dim3(16, 4), 256, 0, stream>>>(hidbf, 512, W2bf, 512, keyb,
                                              (void*)key, 512, 512);

  // ---- fused attention -> ctx into gin[:, 0:512] ----
  attn_fused<<<2048, 512, 0, stream>>>(enc, W1bf, key, Vw, ginbf);

  // ---- GRU matmuls ----
  gemm_bt<0><<<dim3(16, 12), 256, 0, stream>>>(hidbf, 512, whhbf, 512, bhh,
                                               (void*)gh, 1536, 512);
  gemm_bt<0><<<dim3(16, 12), 256, 0, stream>>>(ginbf, 832, wihbf, 832, bih,
                                               (void*)gi, 1536, 832);
  gru_kernel<<<2048 * 512 / 256, 256, 0, stream>>>(gi, gh, hidden, out_h, hnewbf);

  // ---- head: a1 = lrelu(h_new@fc1^T+b) [bf16], y = a1@fc2^T+b -> d_out ----
  gemm_bt<1><<<dim3(16, 3), 256, 0, stream>>>(hnewbf, 512, fc1wbf, 512, fc1bp,
                                              (void*)a1bf, 384, 512);
  gemm_bt<0><<<dim3(16, 1), 256, 0, stream>>>(a1bf, 384, fc2wbf, 384, fc2b,
                                              (void*)out_y, 128, 384);
}

// Round 7
// 1234.154 us; speedup vs baseline: 1.3558x; 1.3558x over previous
//
#include <hip/hip_runtime.h>
#include <hip/hip_bf16.h>

// ---------------------------------------------------------------------------
// Decoder step: attention (enc@W1^T fused tanh/softmax/ctx) + GRU + fc head.
// R3 (resubmitted R4-R6 after infra timeouts): occupancy-first restructure.
//  - logits_kernel: S-quarter tiles (32 rows, 33KB LDS), acc[2][4]/wave,
//    launch_bounds(512,6) -> ~24 waves/CU, 4-deep block overlap.
//  - ctx_kernel: 512 thr, s-split across 8 waves, f32 enc re-read (L3-warm).
//  - gh+gi merged into ONE 384-block launch (fills the chip).
//  - key/fc1/fc2 moved to a 64x64-tile GEMM (4-16x more blocks each).
// All reductions fixed-order deterministic (replay tripwire).
// ---------------------------------------------------------------------------

typedef __attribute__((ext_vector_type(4))) float floatx4;
typedef __attribute__((ext_vector_type(8))) short short8;

#define DEV static __device__ __forceinline__

DEV unsigned short f2bf(float f) {          // fp32 -> bf16, round-nearest-even
  unsigned u = __float_as_uint(f);
  u = u + 0x7fffu + ((u >> 16) & 1u);
  return (unsigned short)(u >> 16);
}
DEV float bf2f(unsigned short s) { return __uint_as_float(((unsigned)s) << 16); }
DEV float tanh_fast(float x) {              // saturates correctly at +-inf
  float e = __expf(2.f * x);
  return 1.f - 2.f / (e + 1.f);
}
DEV float sigmoid_fast(float x) { return 1.f / (1.f + __expf(-x)); }

DEV unsigned pk2(float a, float b) {        // 2x f32 -> packed bf16x2 (RNE)
  float2 f;
  f.x = a;
  f.y = b;
  __hip_bfloat162 h = __float22bfloat162_rn(f);
  return *(unsigned*)&h;
}

// ---------------------------------------------------------------------------
// Fused prep: all fp32->bf16 padded converts + bias folds + embedding gather
// in ONE launch. Segments dispatched by blockIdx ranges.
// ---------------------------------------------------------------------------
DEV void convpad_body(const float* __restrict__ src,
                      unsigned short* __restrict__ dst,
                      int idx, int Nsrc, int Kin, int Kp) {
  int n = idx / Kp, k = idx - n * Kp;
  float v = (k < Kin && n < Nsrc) ? src[(size_t)n * Kin + k] : 0.f;
  dst[idx] = f2bf(v);
}

#define PB_W1 1024
#define PB_W2 1024
#define PB_WIH 4992
#define PB_WHH 3072
#define PB_FC1 768
#define PB_FC2 192
#define PB_HID 4096
#define PB_EMB 2560
#define PB_BIAS 2
#define PREP_BLOCKS (PB_W1 + PB_W2 + PB_WIH + PB_WHH + PB_FC1 + PB_FC2 + PB_HID + PB_EMB + PB_BIAS)

__global__ void prep_all(
    const float* __restrict__ W1w, unsigned short* __restrict__ W1bf,
    const float* __restrict__ W2w, unsigned short* __restrict__ W2bf,
    const float* __restrict__ wih, unsigned short* __restrict__ wihbf,
    const float* __restrict__ whh, unsigned short* __restrict__ whhbf,
    const float* __restrict__ fc1w, unsigned short* __restrict__ fc1wbf,
    const float* __restrict__ fc2w, unsigned short* __restrict__ fc2wbf,
    const float* __restrict__ hidden, unsigned short* __restrict__ hidbf,
    const int* __restrict__ x, const float* __restrict__ embt,
    unsigned short* __restrict__ gin,
    const float* __restrict__ W1b, const float* __restrict__ W2b,
    float* __restrict__ keyb,
    const float* __restrict__ fc1b, float* __restrict__ fc1bp) {
  int bid = blockIdx.x;
  int tid = threadIdx.x;
  if (bid < PB_W1) {
    convpad_body(W1w, W1bf, bid * 256 + tid, 512, 512, 512);
    return;
  }
  bid -= PB_W1;
  if (bid < PB_W2) {
    convpad_body(W2w, W2bf, bid * 256 + tid, 512, 512, 512);
    return;
  }
  bid -= PB_W2;
  if (bid < PB_WIH) {
    convpad_body(wih, wihbf, bid * 256 + tid, 1536, 812, 832);
    return;
  }
  bid -= PB_WIH;
  if (bid < PB_WHH) {
    convpad_body(whh, whhbf, bid * 256 + tid, 1536, 512, 512);
    return;
  }
  bid -= PB_WHH;
  if (bid < PB_FC1) {
    convpad_body(fc1w, fc1wbf, bid * 256 + tid, 300, 512, 512);
    return;
  }
  bid -= PB_FC1;
  if (bid < PB_FC2) {
    convpad_body(fc2w, fc2wbf, bid * 256 + tid, 128, 300, 384);
    return;
  }
  bid -= PB_FC2;
  if (bid < PB_HID) {
    convpad_body(hidden, hidbf, bid * 256 + tid, 2048, 512, 512);
    return;
  }
  bid -= PB_HID;
  if (bid < PB_EMB) {
    int idx = bid * 256 + tid;            // 2048 * 320
    int b = idx / 320, e = idx - b * 320;
    float v = (e < 300) ? embt[(size_t)x[b] * 300 + e] : 0.f;
    gin[(size_t)b * 832 + 512 + e] = f2bf(v);
    return;
  }
  bid -= PB_EMB;
  {
    int i = bid * 256 + tid;
    if (i < 512) keyb[i] = W1b[i] + W2b[i];   // W1_b + W2_b folded into key
    if (i < 384) fc1bp[i] = (i < 300) ? fc1b[i] : 0.f;
  }
}

// ---------------------------------------------------------------------------
// gemm_body: the verified 128x128-tile bf16 GEMM inner structure as a device
// function (used by the merged gh+gi kernel). C[M,N] = A@B^T + bias.
// ---------------------------------------------------------------------------
DEV void gemm_body128(const unsigned short* __restrict__ A, int lda,
                      const unsigned short* __restrict__ Bm, int ldb,
                      const float* __restrict__ bias,
                      float* __restrict__ Cp, int ldc, int K,
                      int bm, int bn, unsigned short* As, unsigned short* Bs) {
  int tid = threadIdx.x;
  int lane = tid & 63, wave = tid >> 6;
  int l15 = lane & 15, l4 = lane >> 4;
  int wm = (wave >> 1) * 64, wn = (wave & 1) * 64;

  floatx4 zero = {0.f, 0.f, 0.f, 0.f};
  floatx4 acc[4][4];
#pragma unroll
  for (int i = 0; i < 4; ++i)
#pragma unroll
    for (int j = 0; j < 4; ++j) acc[i][j] = zero;

  int row = tid >> 1;                 // staging: thread -> (row, 4 granules)
  int gc0 = (tid & 1) * 4;
  const unsigned short* Aptr = A + (size_t)(bm + row) * lda + gc0 * 8;
  const unsigned short* Bptr = Bm + (size_t)(bn + row) * ldb + gc0 * 8;
  int rslot7 = row & 7, lslot7 = l15 & 7;

  int nk = K >> 6;
  for (int kt = 0; kt < nk; ++kt) {
#pragma unroll
    for (int i = 0; i < 4; ++i) {
      int slot = (gc0 + i) ^ rslot7;
      *(uint4*)&As[row * 64 + slot * 8] = *(const uint4*)(Aptr + kt * 64 + i * 8);
      *(uint4*)&Bs[row * 64 + slot * 8] = *(const uint4*)(Bptr + kt * 64 + i * 8);
    }
    __syncthreads();
#pragma unroll
    for (int ks = 0; ks < 2; ++ks) {
      int slot = (ks * 4 + l4) ^ lslot7;
      short8 av[4], bv[4];
#pragma unroll
      for (int mt = 0; mt < 4; ++mt)
        av[mt] = *(const short8*)&As[(wm + mt * 16 + l15) * 64 + slot * 8];
#pragma unroll
      for (int nt = 0; nt < 4; ++nt)
        bv[nt] = *(const short8*)&Bs[(wn + nt * 16 + l15) * 64 + slot * 8];
#pragma unroll
      for (int mt = 0; mt < 4; ++mt)
#pragma unroll
        for (int nt = 0; nt < 4; ++nt)
          acc[mt][nt] = __builtin_amdgcn_mfma_f32_16x16x32_bf16(
              av[mt], bv[nt], acc[mt][nt], 0, 0, 0);
    }
    __syncthreads();
  }

#pragma unroll
  for (int nt = 0; nt < 4; ++nt) {
    int n = bn + wn + nt * 16 + l15;
    float bvv = bias[n];
#pragma unroll
    for (int mt = 0; mt < 4; ++mt) {
#pragma unroll
      for (int r = 0; r < 4; ++r) {
        int m = bm + wm + mt * 16 + l4 * 4 + r;
        Cp[(size_t)m * ldc + n] = acc[mt][nt][r] + bvv;
      }
    }
  }
}

// Merged GRU matmuls: y<12 -> gh = hid@whh^T + bhh ; y>=12 -> gi = gin@wih^T
// + bih. 384 blocks fill the chip; both write [2048,1536] f32.
__global__ __launch_bounds__(256, 3) void gemm_gru(
    const unsigned short* __restrict__ hidbf,
    const unsigned short* __restrict__ whhbf, const float* __restrict__ bhh,
    float* __restrict__ gh,
    const unsigned short* __restrict__ ginbf,
    const unsigned short* __restrict__ wihbf, const float* __restrict__ bih,
    float* __restrict__ gi) {
  __shared__ unsigned short As[128 * 64];
  __shared__ unsigned short Bs[128 * 64];
  int bm = blockIdx.x * 128;
  int y = blockIdx.y;
  if (y < 12) {
    gemm_body128(hidbf, 512, whhbf, 512, bhh, gh, 1536, 512, bm, y * 128, As, Bs);
  } else {
    gemm_body128(ginbf, 832, wihbf, 832, bih, gi, 1536, 832, bm, (y - 12) * 128,
                 As, Bs);
  }
}

// ---------------------------------------------------------------------------
// 64x64-tile bf16 GEMM for the small matmuls (key/fc1/fc2): 256 threads,
// wave tile 32x32. 4-16x more blocks than the 128-tile version -> less
// launch-latency on a 256-CU chip. EPI 0: f32. EPI 1: lrelu -> bf16.
// ---------------------------------------------------------------------------
template <int EPI>
__global__ __launch_bounds__(256, 4) void gemm64(
    const unsigned short* __restrict__ A, int lda,
    const unsigned short* __restrict__ Bm, int ldb,
    const float* __restrict__ bias,
    void* __restrict__ Cp, int ldc, int K) {
  __shared__ unsigned short As[64 * 64];
  __shared__ unsigned short Bs[64 * 64];
  int tid = threadIdx.x;
  int bm = blockIdx.x * 64, bn = blockIdx.y * 64;
  int lane = tid & 63, wave = tid >> 6;
  int l15 = lane & 15, l4 = lane >> 4;
  int wm = (wave >> 1) * 32, wn = (wave & 1) * 32;

  floatx4 zero = {0.f, 0.f, 0.f, 0.f};
  floatx4 acc[2][2];
#pragma unroll
  for (int i = 0; i < 2; ++i)
#pragma unroll
    for (int j = 0; j < 2; ++j) acc[i][j] = zero;

  int row = tid >> 2;                 // 64 rows, 4 threads/row, 2 granules ea
  int gc0 = (tid & 3) * 2;
  const unsigned short* Aptr = A + (size_t)(bm + row) * lda + gc0 * 8;
  const unsigned short* Bptr = Bm + (size_t)(bn + row) * ldb + gc0 * 8;
  int rslot7 = row & 7, lslot7 = l15 & 7;

  int nk = K >> 6;
  for (int kt = 0; kt < nk; ++kt) {
#pragma unroll
    for (int i = 0; i < 2; ++i) {
      int slot = (gc0 + i) ^ rslot7;
      *(uint4*)&As[row * 64 + slot * 8] = *(const uint4*)(Aptr + kt * 64 + i * 8);
      *(uint4*)&Bs[row * 64 + slot * 8] = *(const uint4*)(Bptr + kt * 64 + i * 8);
    }
    __syncthreads();
#pragma unroll
    for (int ks = 0; ks < 2; ++ks) {
      int slot = (ks * 4 + l4) ^ lslot7;
      short8 av[2], bv[2];
#pragma unroll
      for (int mt = 0; mt < 2; ++mt)
        av[mt] = *(const short8*)&As[(wm + mt * 16 + l15) * 64 + slot * 8];
#pragma unroll
      for (int nt = 0; nt < 2; ++nt)
        bv[nt] = *(const short8*)&Bs[(wn + nt * 16 + l15) * 64 + slot * 8];
#pragma unroll
      for (int mt = 0; mt < 2; ++mt)
#pragma unroll
        for (int nt = 0; nt < 2; ++nt)
          acc[mt][nt] = __builtin_amdgcn_mfma_f32_16x16x32_bf16(
              av[mt], bv[nt], acc[mt][nt], 0, 0, 0);
    }
    __syncthreads();
  }

#pragma unroll
  for (int nt = 0; nt < 2; ++nt) {
    int n = bn + wn + nt * 16 + l15;
    float bvv = bias[n];
#pragma unroll
    for (int mt = 0; mt < 2; ++mt) {
#pragma unroll
      for (int r = 0; r < 4; ++r) {
        int m = bm + wm + mt * 16 + l4 * 4 + r;
        float v = acc[mt][nt][r] + bvv;
        if (EPI == 1) {
          v = v > 0.f ? v : 0.01f * v;
          ((unsigned short*)Cp)[(size_t)m * ldc + n] = f2bf(v);
        } else {
          ((float*)Cp)[(size_t)m * ldc + n] = v;
        }
      }
    }
  }
}

// ---------------------------------------------------------------------------
// logits_kernel: block = (batch b, S-quarter q). 512 threads = 8 waves.
// Stage enc[b, q*32 .. +32) f32 -> 32KB bf16 LDS (XOR-swizzled). GEMM: wave
// owns 64 cols, acc[2][4] (32 VGPR). Epilogue tanh(score+key) dot Vw ->
// per-wave slab, fixed-order sum -> logits[b][s]. 33KB LDS + VGPR<=85
// (launch_bounds 512,6) -> ~24 waves/CU, deep block-level overlap.
// ---------------------------------------------------------------------------
__global__ __launch_bounds__(512, 6) void logits_kernel(
    const float* __restrict__ enc, const unsigned short* __restrict__ W1b16,
    const float* __restrict__ key, const float* __restrict__ Vw,
    float* __restrict__ logits) {
  __shared__ unsigned short Albs[32 * 512];      // 32KB
  __shared__ float lds_part[8 * 32];             // per-wave logit partials

  int b = blockIdx.x, q = blockIdx.y;
  int tid = threadIdx.x;
  const float* encb = enc + ((size_t)b * 128 + (size_t)q * 32) * 512;

  // ---- stage 32x512 f32 -> bf16 swizzled 16B granules (4 iters) ----
#pragma unroll
  for (int it = 0; it < 4; ++it) {
    int g = it * 512 + tid;          // granule id 0..2047
    int m = g >> 6, gc = g & 63;
    const float4* src = (const float4*)(encb + (size_t)g * 8);
    float4 lo = src[0], hi = src[1];
    uint4 pk;
    pk.x = pk2(lo.x, lo.y);
    pk.y = pk2(lo.z, lo.w);
    pk.z = pk2(hi.x, hi.y);
    pk.w = pk2(hi.z, hi.w);
    int slot = gc ^ (m & 7);
    *(uint4*)&Albs[m * 512 + slot * 8] = pk;
  }
  __syncthreads();

  // ---- GEMM: 32 rows x 512 cols, barrier-free K-loop ----
  int wave = tid >> 6, lane = tid & 63;
  int l15 = lane & 15, l4 = lane >> 4, lslot7 = l15 & 7;
  int n0 = wave * 64;

  floatx4 zero = {0.f, 0.f, 0.f, 0.f};
  floatx4 acc[2][4];
#pragma unroll
  for (int i = 0; i < 2; ++i)
#pragma unroll
    for (int j = 0; j < 4; ++j) acc[i][j] = zero;

#pragma unroll 2
  for (int kt = 0; kt < 16; ++kt) {
    int slot = (kt * 4 + l4) ^ lslot7;
    short8 av[2], bv[4];
#pragma unroll
    for (int nt = 0; nt < 4; ++nt) {   // B frags from global (L2-hot W1 bf16)
      int n = n0 + nt * 16 + l15;
      bv[nt] = *(const short8*)(W1b16 + (size_t)n * 512 + kt * 32 + l4 * 8);
    }
#pragma unroll
    for (int mt = 0; mt < 2; ++mt)
      av[mt] = *(const short8*)&Albs[(mt * 16 + l15) * 512 + slot * 8];
#pragma unroll
    for (int mt = 0; mt < 2; ++mt)
#pragma unroll
      for (int nt = 0; nt < 4; ++nt)
        acc[mt][nt] = __builtin_amdgcn_mfma_f32_16x16x32_bf16(
            av[mt], bv[nt], acc[mt][nt], 0, 0, 0);
  }

  // ---- epilogue: per-wave 64-col dot of tanh(score+key) with Vw ----
  float kb[4], vwl[4];
#pragma unroll
  for (int nt = 0; nt < 4; ++nt) {
    int col = n0 + nt * 16 + l15;
    kb[nt] = key[(size_t)b * 512 + col];
    vwl[nt] = Vw[col];
  }
#pragma unroll
  for (int mt = 0; mt < 2; ++mt) {
#pragma unroll
    for (int r = 0; r < 4; ++r) {
      float c = 0.f;
#pragma unroll
      for (int nt = 0; nt < 4; ++nt)
        c += tanh_fast(acc[mt][nt][r] + kb[nt]) * vwl[nt];
      c += __shfl_xor(c, 1, 64);
      c += __shfl_xor(c, 2, 64);
      c += __shfl_xor(c, 4, 64);
      c += __shfl_xor(c, 8, 64);
      if (l15 == 0) lds_part[wave * 32 + mt * 16 + l4 * 4 + r] = c;
    }
  }
  __syncthreads();

  if (tid < 32) {                      // fixed-order sum: deterministic
    float l = 0.f;
#pragma unroll
    for (int w = 0; w < 8; ++w) l += lds_part[w * 32 + tid];
    logits[(size_t)b * 128 + q * 32 + tid] = l;
  }
}

// ---------------------------------------------------------------------------
// ctx_kernel: block per batch b, 512 threads (8 waves). Wave 0: softmax over
// 128 logits -> attw. Then wave w sums s in [w*16,w*16+16): lane reads 2x
// float4 of enc f32 (coalesced, L3-warm), partials in LDS, fixed-order final
// reduce -> gin[:, 0:512] bf16. Tiny LDS + low VGPR -> full occupancy.
// ---------------------------------------------------------------------------
__global__ __launch_bounds__(512, 8) void ctx_kernel(
    const float* __restrict__ enc, const float* __restrict__ logits,
    unsigned short* __restrict__ gin) {
  __shared__ float attw[128];
  __shared__ float ctxp[8 * 512];
  int b = blockIdx.x, tid = threadIdx.x;
  int wave = tid >> 6, lane = tid & 63;

  if (tid < 64) {
    float l0 = logits[(size_t)b * 128 + tid];
    float l1 = logits[(size_t)b * 128 + 64 + tid];
    float mx = fmaxf(l0, l1);
#pragma unroll
    for (int o = 32; o >= 1; o >>= 1) mx = fmaxf(mx, __shfl_xor(mx, o, 64));
    float e0 = __expf(l0 - mx), e1 = __expf(l1 - mx);
    float s = e0 + e1;
#pragma unroll
    for (int o = 32; o >= 1; o >>= 1) s += __shfl_xor(s, o, 64);
    float inv = 1.f / s;
    attw[tid] = e0 * inv;
    attw[tid + 64] = e1 * inv;
  }
  __syncthreads();

  const float* encb = enc + (size_t)b * 128 * 512;
  {
    float4 cx0 = {0.f, 0.f, 0.f, 0.f}, cx1 = {0.f, 0.f, 0.f, 0.f};
    const float* ep = encb + (size_t)(wave * 16) * 512 + lane * 4;
#pragma unroll 4
    for (int i = 0; i < 16; ++i) {
      float w = attw[wave * 16 + i];
      float4 v0 = *(const float4*)(ep + (size_t)i * 512);
      float4 v1 = *(const float4*)(ep + (size_t)i * 512 + 256);
      cx0.x += w * v0.x;
      cx0.y += w * v0.y;
      cx0.z += w * v0.z;
      cx0.w += w * v0.w;
      cx1.x += w * v1.x;
      cx1.y += w * v1.y;
      cx1.z += w * v1.z;
      cx1.w += w * v1.w;
    }
    *(float4*)&ctxp[wave * 512 + lane * 4] = cx0;
    *(float4*)&ctxp[wave * 512 + 256 + lane * 4] = cx1;
  }
  __syncthreads();

  {
    int h = tid;                        // 512 cols, fixed-order sum
    float s = 0.f;
#pragma unroll
    for (int w = 0; w < 8; ++w) s += ctxp[w * 512 + h];
    gin[(size_t)b * 832 + h] = f2bf(s);
  }
}

// ---------------------------------------------------------------------------
// GRU elementwise.
// ---------------------------------------------------------------------------
__global__ void gru_kernel(const float* __restrict__ gi,
                           const float* __restrict__ gh,
                           const float* __restrict__ hidden,
                           float* __restrict__ outh,
                           unsigned short* __restrict__ hnewbf) {
  int idx = blockIdx.x * 256 + threadIdx.x;   // 2048*512
  int b = idx >> 9, h = idx & 511;
  const float* gib = gi + (size_t)b * 1536;
  const float* ghb = gh + (size_t)b * 1536;
  float r = sigmoid_fast(gib[h] + ghb[h]);
  float z = sigmoid_fast(gib[512 + h] + ghb[512 + h]);
  float n = tanh_fast(gib[1024 + h] + r * ghb[1024 + h]);
  float h0 = hidden[idx];
  float hn = (1.f - z) * n + z * h0;
  outh[idx] = hn;
  hnewbf[idx] = f2bf(hn);
}

// ---------------------------------------------------------------------------
extern "C" void kernel_launch(void* const* d_in, const int* in_sizes, int n_in,
                              void* d_out, int out_size, void* d_ws,
                              size_t ws_size, hipStream_t stream) {
  const int* x = (const int*)d_in[0];
  const float* hidden = (const float*)d_in[1];   // (1,2048,512)
  const float* enc = (const float*)d_in[2];      // (2048,128,512)
  const float* embt = (const float*)d_in[3];     // (128,300)
  const float* W1w = (const float*)d_in[4];
  const float* W1b = (const float*)d_in[5];
  const float* W2w = (const float*)d_in[6];
  const float* W2b = (const float*)d_in[7];
  const float* Vw = (const float*)d_in[8];
  // d_in[9] = V_b: unused (softmax shift-invariant)
  const float* wih = (const float*)d_in[10];     // (1536,812)
  const float* whh = (const float*)d_in[11];     // (1536,512)
  const float* bih = (const float*)d_in[12];
  const float* bhh = (const float*)d_in[13];
  const float* fc1w = (const float*)d_in[14];    // (300,512)
  const float* fc1b = (const float*)d_in[15];
  const float* fc2w = (const float*)d_in[16];    // (128,300)
  const float* fc2b = (const float*)d_in[17];

  float* out_y = (float*)d_out;                  // (2048,128)
  float* out_h = out_y + 2048 * 128;             // (2048,512)

  char* ws = (char*)d_ws;
  size_t o = 0;
  auto alloc = [&](size_t bytes) {
    size_t r = o;
    o += (bytes + 255) & ~(size_t)255;
    return r;
  };
  unsigned short* W1bf = (unsigned short*)(ws + alloc(512 * 512 * 2));
  unsigned short* W2bf = (unsigned short*)(ws + alloc(512 * 512 * 2));
  unsigned short* wihbf = (unsigned short*)(ws + alloc(1536 * 832 * 2));
  unsigned short* whhbf = (unsigned short*)(ws + alloc(1536 * 512 * 2));
  unsigned short* fc1wbf = (unsigned short*)(ws + alloc(384 * 512 * 2));
  unsigned short* fc2wbf = (unsigned short*)(ws + alloc(128 * 384 * 2));
  unsigned short* hidbf = (unsigned short*)(ws + alloc(2048 * 512 * 2));
  unsigned short* ginbf = (unsigned short*)(ws + alloc((size_t)2048 * 832 * 2));
  float* keyb = (float*)(ws + alloc(512 * 4));
  float* fc1bp = (float*)(ws + alloc(384 * 4));
  float* key = (float*)(ws + alloc((size_t)2048 * 512 * 4));
  float* logits = (float*)(ws + alloc((size_t)2048 * 128 * 4));
  float* gi = (float*)(ws + alloc((size_t)2048 * 1536 * 4));
  float* gh = (float*)(ws + alloc((size_t)2048 * 1536 * 4));
  unsigned short* hnewbf = (unsigned short*)(ws + alloc(2048 * 512 * 2));
  unsigned short* a1bf = (unsigned short*)(ws + alloc((size_t)2048 * 384 * 2));

  // ---- prep: all bf16 conversions + biases + embedding in ONE launch ----
  prep_all<<<PREP_BLOCKS, 256, 0, stream>>>(
      W1w, W1bf, W2w, W2bf, wih, wihbf, whh, whhbf, fc1w, fc1wbf, fc2w, fc2wbf,
      hidden, hidbf, x, embt, ginbf, W1b, W2b, keyb, fc1b, fc1bp);

  // ---- key = h0 @ W2^T + (W2_b + W1_b): 64-tile, 256 blocks ----
  gemm64<0><<<dim3(32, 8), 256, 0, stream>>>(hidbf, 512, W2bf, 512, keyb,
                                             (void*)key, 512, 512);

  // ---- attention: logits (high-occupancy MFMA) then softmax+ctx (BW) ----
  logits_kernel<<<dim3(2048, 4), 512, 0, stream>>>(enc, W1bf, key, Vw, logits);
  ctx_kernel<<<2048, 512, 0, stream>>>(enc, logits, ginbf);

  // ---- GRU matmuls: ONE merged launch, 384 blocks ----
  gemm_gru<<<dim3(16, 24), 256, 0, stream>>>(hidbf, whhbf, bhh, gh, ginbf,
                                             wihbf, bih, gi);
  gru_kernel<<<2048 * 512 / 256, 256, 0, stream>>>(gi, gh, hidden, out_h, hnewbf);

  // ---- head: a1 = lrelu(h_new@fc1^T+b) [bf16], y = a1@fc2^T+b -> d_out ----
  gemm64<1><<<dim3(32, 6), 256, 0, stream>>>(hnewbf, 512, fc1wbf, 512, fc1bp,
                                             (void*)a1bf, 384, 512);
  gemm64<0><<<dim3(32, 2), 256, 0, stream>>>(a1bf, 384, fc2wbf, 384, fc2b,
                                             (void*)out_y, 128, 384);
}